// Round 2
// baseline (372.041 us; speedup 1.0000x reference)
//
#include <hip/hip_runtime.h>

// MaskedPooling: out[b,d] = sum_t x[b,t,d]*keep[b,t] / sum_t keep[b,t]
// x: [B=32, T=4096, D=512] fp32; mask: [B,T] int32 (nonzero = excluded)
//
// Split-K over T: kernel1 writes per-(b,split) float4 partials to d_ws
// (no atomics), kernel2 reduces 64 partials/column + scales by 1/denom.

#define BB 32
#define TT 4096
#define DD 512
#define SPLITS 64
#define ROWS (TT / SPLITS)   // 64 rows per block
#define D4 (DD / 4)          // 128 float4 columns

__global__ __launch_bounds__(128) void masked_pool_partial(
    const float* __restrict__ x, const int* __restrict__ mask,
    float4* __restrict__ ws)
{
    __shared__ float s_keep[ROWS];
    const int b   = blockIdx.x;
    const int s   = blockIdx.y;
    const int tid = threadIdx.x;          // 0..127 -> one float4 column
    const int t0  = s * ROWS;

    if (tid < ROWS)
        s_keep[tid] = (mask[b * TT + t0 + tid] == 0) ? 1.0f : 0.0f;
    __syncthreads();

    const float4* xp = (const float4*)x + ((size_t)b * TT + t0) * D4 + tid;

    float4 acc = make_float4(0.f, 0.f, 0.f, 0.f);
    #pragma unroll 8
    for (int r = 0; r < ROWS; ++r) {
        const float  k = s_keep[r];              // LDS broadcast
        const float4 v = xp[(size_t)r * D4];     // coalesced 16 B/lane
        acc.x += k * v.x;
        acc.y += k * v.y;
        acc.z += k * v.z;
        acc.w += k * v.w;
    }

    ws[((size_t)b * SPLITS + s) * D4 + tid] = acc;   // plain store, no atomics
}

__global__ __launch_bounds__(256) void masked_pool_reduce(
    const float4* __restrict__ ws, const int* __restrict__ mask,
    float4* __restrict__ out)
{
    const int b   = blockIdx.x;
    const int tid = threadIdx.x;

    // denom[b] = count of kept positions (mask == 0)
    int cnt = 0;
    #pragma unroll
    for (int t = tid; t < TT; t += 256) cnt += (mask[b * TT + t] == 0) ? 1 : 0;
    #pragma unroll
    for (int off = 32; off > 0; off >>= 1) cnt += __shfl_down(cnt, off, 64);

    __shared__ int s_cnt[4];
    if ((tid & 63) == 0) s_cnt[tid >> 6] = cnt;
    __syncthreads();
    const float inv = 1.0f / (float)(s_cnt[0] + s_cnt[1] + s_cnt[2] + s_cnt[3]);

    if (tid < D4) {
        const float4* p = ws + (size_t)b * SPLITS * D4 + tid;
        float4 acc = make_float4(0.f, 0.f, 0.f, 0.f);
        #pragma unroll 8
        for (int s = 0; s < SPLITS; ++s) {
            const float4 v = p[(size_t)s * D4];
            acc.x += v.x; acc.y += v.y; acc.z += v.z; acc.w += v.w;
        }
        acc.x *= inv; acc.y *= inv; acc.z *= inv; acc.w *= inv;
        out[(size_t)b * D4 + tid] = acc;
    }
}

extern "C" void kernel_launch(void* const* d_in, const int* in_sizes, int n_in,
                              void* d_out, int out_size, void* d_ws, size_t ws_size,
                              hipStream_t stream) {
    const float* x    = (const float*)d_in[0];
    const int*   mask = (const int*)d_in[1];
    float4*      ws   = (float4*)d_ws;     // needs 32*64*128*16 B = 4 MiB
    float4*      out  = (float4*)d_out;

    dim3 grid(BB, SPLITS);
    masked_pool_partial<<<grid, 128, 0, stream>>>(x, mask, ws);
    masked_pool_reduce<<<BB, 256, 0, stream>>>(ws, mask, out);
}